// Round 6
// baseline (411.726 us; speedup 1.0000x reference)
//
#include <hip/hip_runtime.h>
#include <cstdint>
#include <cstddef>

// SecureFeedForward: out = relu(x @ W1^T + b1) @ W2^T + b2
// x:[16384,1024] f32, W1:[4096,1024], W2:[1024,4096], out:[16384,1024] f32.
// R6: 32x32x16 bf16 MFMA (higher pipe ceiling, 4x fewer instrs), balanced
// 6-read/8-MFMA phases (1 kstep=16 each), uniform stage->read distance 6
// phases with vmcnt(8) at every even phase (12 gloads in flight), direct
// bf16 stores (32-lane x 2B = 64B contiguous segments).

typedef __bf16 bf16x8 __attribute__((ext_vector_type(8)));
typedef float f32x16 __attribute__((ext_vector_type(16)));

__device__ __forceinline__ unsigned short f32_to_bf16_rn(float f) {
  union { float f; unsigned int u; } v; v.f = f;
  unsigned int u = v.u;
  u += 0x7fffu + ((u >> 16) & 1u);   // round-to-nearest-even
  return (unsigned short)(u >> 16);
}

__global__ void cvt_all(const float* __restrict__ x,
                        const float* __restrict__ w1,
                        const float* __restrict__ w2,
                        unsigned short* __restrict__ xb,
                        unsigned short* __restrict__ w1b,
                        unsigned short* __restrict__ w2b,
                        int nx4, int nw4) {
  const int stride = gridDim.x * blockDim.x;
  int i = blockIdx.x * blockDim.x + threadIdx.x;
  const int total = nx4 + 2 * nw4;
  for (; i < total; i += stride) {
    const float* src; unsigned short* dst; int j;
    if (i < nx4) { src = x; dst = xb; j = i; }
    else if (i < nx4 + nw4) { src = w1; dst = w1b; j = i - nx4; }
    else { src = w2; dst = w2b; j = i - nx4 - nw4; }
    const float4 v = reinterpret_cast<const float4*>(src)[j];
    ushort4 o;
    o.x = f32_to_bf16_rn(v.x);
    o.y = f32_to_bf16_rn(v.y);
    o.z = f32_to_bf16_rn(v.z);
    o.w = f32_to_bf16_rn(v.w);
    reinterpret_cast<ushort4*>(dst)[j] = o;
  }
}

__device__ __forceinline__ void gload_lds16(const void* g, void* l) {
  __builtin_amdgcn_global_load_lds(
      (const __attribute__((address_space(1))) void*)g,
      (__attribute__((address_space(3))) void*)l,
      16, 0, 0);
}

#define VMCNT8 asm volatile("s_waitcnt vmcnt(8)" ::: "memory")
#define VMCNT0 asm volatile("s_waitcnt vmcnt(0)" ::: "memory")

// LDS half-planes: A(buf,kh), B(buf,kh); each 16 KiB = [256 rows][64B].
#define APL(BUF, KH) (((BUF)*2 + (KH)) * 16384)
#define BPL(BUF, KH) (65536 + ((BUF)*2 + (KH)) * 16384)

// Stage one half-plane (256 rows x 32 bf16). Linear LDS dest (HW: uniform
// base + lane*16); global source pre-swizzled to match the ds_read swizzle.
#define STAGE(PLANEOFF, GROW, KB) do {                                          \
    gload_lds16((GROW) + (size_t)srow0 * pitch + (KB) + scol0,                  \
                lds + (PLANEOFF) + ldsw0);                                      \
    gload_lds16((GROW) + (size_t)srow1 * pitch + (KB) + scol1,                  \
                lds + (PLANEOFF) + ldsw1);                                      \
  } while (0)

// One phase = one kstep (K=16): 4 A-frag + 2 B-frag ds_read_b128, 1 STAGE,
// barrier, 8 MFMA (4 mb x 2 nb), [vmcnt(8) on even phases], barrier.
#define PHASE(BUF, KST, STAGE_STMT, DOVM) do {                                  \
    const unsigned char* pA_ =                                                  \
        lds + APL(BUF, (KST) >> 1) + wroff + lrow64 + ach[(KST) & 1];           \
    const unsigned char* pB_ =                                                  \
        lds + BPL(BUF, (KST) >> 1) + wcoff + lrow64 + ach[(KST) & 1];           \
    _Pragma("unroll") for (int mb_ = 0; mb_ < 4; ++mb_)                         \
      a_[mb_] = *(const bf16x8*)(pA_ + (mb_ << 11));                            \
    b_[0] = *(const bf16x8*)(pB_);                                              \
    b_[1] = *(const bf16x8*)(pB_ + 2048);                                       \
    STAGE_STMT;                                                                 \
    __builtin_amdgcn_sched_barrier(0);                                          \
    __builtin_amdgcn_s_barrier();                                               \
    __builtin_amdgcn_sched_barrier(0);                                          \
    __builtin_amdgcn_s_setprio(1);                                              \
    _Pragma("unroll") for (int mb_ = 0; mb_ < 4; ++mb_) {                       \
      acc[mb_][0] = __builtin_amdgcn_mfma_f32_32x32x16_bf16(                    \
          a_[mb_], b_[0], acc[mb_][0], 0, 0, 0);                                \
      acc[mb_][1] = __builtin_amdgcn_mfma_f32_32x32x16_bf16(                    \
          a_[mb_], b_[1], acc[mb_][1], 0, 0, 0);                                \
    }                                                                           \
    __builtin_amdgcn_s_setprio(0);                                              \
    if (DOVM) { VMCNT8; }                                                       \
    __builtin_amdgcn_sched_barrier(0);                                          \
    __builtin_amdgcn_s_barrier();                                               \
  } while (0)

// A:[M,K] bf16 row-major, B:[N,K] bf16 row-major (B^T layout), K-contiguous.
// C = A @ B^T + bias; RELU_BF16_OUT: relu + bf16 store, else f32 store.
template <int RELU_BF16_OUT, int NBN>
__global__ __launch_bounds__(512, 2) void gemm8(
    const unsigned short* __restrict__ A,
    const unsigned short* __restrict__ B,
    const float* __restrict__ bias,
    void* __restrict__ Cout,
    int K) {
  constexpr int N = NBN * 256;
  __shared__ unsigned char lds[131072];

  const int tid = threadIdx.x;
  const int l = tid & 63;
  const int w = tid >> 6;        // wave 0..7
  const int wr = w >> 2;         // 0..1 (M half: 128 rows)
  const int wc = w & 3;          // 0..3 (N quarter: 64 cols)

  // XCD-aware bijective swizzle (gridDim.x % 8 == 0 by launch config)
  const int nwg = gridDim.x;
  const int cpx = nwg >> 3;
  const int bid = blockIdx.x;
  const int swz = (bid & 7) * cpx + (bid >> 3);
  const int bmi = swz / NBN;
  const int bni = swz % NBN;

  const size_t pitch = (size_t)K * 2;  // bytes per row (A and B share K)
  const char* Ag = (const char*)A + (size_t)(bmi << 8) * pitch;
  const char* Bg = (const char*)B + (size_t)(bni << 8) * pitch;

  // --- staging constants; LDS swizzle involution: chunk ^= (row>>1)&3 ---
  const int sd0 = tid << 4;
  const int sd1 = sd0 + 8192;
  const int srow0 = sd0 >> 6;
  const int srow1 = sd1 >> 6;
  const int scol0 = (sd0 & 63) ^ (((sd0 >> 7) & 3) << 4);  // pre-swizzled src
  const int scol1 = (sd1 & 63) ^ (((sd1 >> 7) & 3) << 4);
  const int ldsw0 = (w << 10);
  const int ldsw1 = 8192 + (w << 10);

  // --- fragment read constants (32x32x16) ---
  // A: row = wr*128 + mb*32 + (l&31); k-chunk c = (kst&1)*2 + (l>>5);
  // phys byte = row*64 + 16*(c ^ ((row>>1)&3)).
  const int lrow64 = (l & 31) << 6;
  const int sxor = (l >> 1) & 3;              // ((l&31)>>1)&3
  int ach[2];
  ach[0] = ((0 * 2 + (l >> 5)) ^ sxor) << 4;
  ach[1] = ((1 * 2 + (l >> 5)) ^ sxor) << 4;
  const int wroff = wr << 13;   // wr * 128 rows * 64B
  const int wcoff = wc << 12;   // wc * 64 rows * 64B

  f32x16 acc[4][2];
#pragma unroll
  for (int mb = 0; mb < 4; ++mb)
#pragma unroll
    for (int nb = 0; nb < 2; ++nb) { f32x16 z = 0.f; acc[mb][nb] = z; }
  bf16x8 a_[4];
  bf16x8 b_[2];

  const int nt = K >> 6;  // K-tiles of 64 (>= 4, even)

  // --- prologue: 6 half-planes (t0 all 4 + t1's kh0 pair), FIFO order ---
  STAGE(APL(0, 0), Ag, 0);     // A00 <- t0
  STAGE(BPL(0, 0), Bg, 0);     // B00 <- t0
  STAGE(APL(0, 1), Ag, 64);    // A01 <- t0
  STAGE(BPL(0, 1), Bg, 64);    // B01 <- t0
  STAGE(APL(1, 0), Ag, 128);   // A10 <- t1
  STAGE(BPL(1, 0), Bg, 128);   // B10 <- t1
  VMCNT8;                      // retires A00,B00 (12 -> 8 outstanding)
  __builtin_amdgcn_s_barrier();

  // --- main loop: 2 K-tiles / iteration, 8 balanced phases ---
  // Stage targets (uniform 6-phase stage->read distance, 1 phase after last
  // read): P1:A11<-t1h1 P2:B11<-t1h1 P3:A00<-t2h0 P4:B00<-t2h0 P5:A01<-t2h1
  // P6:B01<-t2h1 P7:A10<-t3h0 P8:B10<-t3h0. vmcnt(8) at P2/P4/P6/P8 retires
  // exactly the pair needed one phase later.
  for (int it = 0; it < (nt >> 1); ++it) {
    const int t1 = 2 * it + 1;
    int t2 = 2 * it + 2; if (t2 >= nt) t2 = nt - 1;  // clamped dead prefetch
    int t3 = 2 * it + 3; if (t3 >= nt) t3 = nt - 1;  // (L2-hot, never read)
    const int kb1 = t1 << 7;
    const int kb2 = t2 << 7;
    const int kb3 = t3 << 7;

    PHASE(0, 0, STAGE(APL(1, 1), Ag, kb1 + 64), 0);  // P1
    PHASE(0, 1, STAGE(BPL(1, 1), Bg, kb1 + 64), 1);  // P2
    PHASE(0, 2, STAGE(APL(0, 0), Ag, kb2), 0);       // P3
    PHASE(0, 3, STAGE(BPL(0, 0), Bg, kb2), 1);       // P4
    PHASE(1, 0, STAGE(APL(0, 1), Ag, kb2 + 64), 0);  // P5
    PHASE(1, 1, STAGE(BPL(0, 1), Bg, kb2 + 64), 1);  // P6
    PHASE(1, 2, STAGE(APL(1, 0), Ag, kb3), 0);       // P7
    PHASE(1, 3, STAGE(BPL(1, 0), Bg, kb3), 1);       // P8
  }

  // --- epilogue: C col = l&31 (+nb*32), row = (reg&3)+8*(reg>>2)+4*(l>>5) ---
  const int crow_b = (bmi << 8) + (wr << 7) + ((l >> 5) << 2);
  const int ccol_b = (bni << 8) + (wc << 6) + (l & 31);

  if (RELU_BF16_OUT) {
    unsigned short* C = (unsigned short*)Cout;
    float bv[2];
    bv[0] = bias[ccol_b];
    bv[1] = bias[ccol_b + 32];
#pragma unroll
    for (int mb = 0; mb < 4; ++mb) {
#pragma unroll
      for (int nb = 0; nb < 2; ++nb) {
        const int col = ccol_b + (nb << 5);
#pragma unroll
        for (int reg = 0; reg < 16; ++reg) {
          const int row = crow_b + (mb << 5) + (reg & 3) + ((reg >> 2) << 3);
          const float v = fmaxf(acc[mb][nb][reg] + bv[nb], 0.0f);
          C[(size_t)row * N + col] = f32_to_bf16_rn(v);
        }
      }
    }
  } else {
    float* C = (float*)Cout;
    float bv[2];
    bv[0] = bias[ccol_b];
    bv[1] = bias[ccol_b + 32];
#pragma unroll
    for (int mb = 0; mb < 4; ++mb) {
#pragma unroll
      for (int nb = 0; nb < 2; ++nb) {
        const int col = ccol_b + (nb << 5);
#pragma unroll
        for (int reg = 0; reg < 16; ++reg) {
          const int row = crow_b + (mb << 5) + (reg & 3) + ((reg >> 2) << 3);
          C[(size_t)row * N + col] = acc[mb][nb][reg] + bv[nb];
        }
      }
    }
  }
  VMCNT0;  // drain dead prefetch gloads before LDS dealloc at endpgm
}

extern "C" void kernel_launch(void* const* d_in, const int* in_sizes, int n_in,
                              void* d_out, int out_size, void* d_ws, size_t ws_size,
                              hipStream_t stream) {
  const float* x  = (const float*)d_in[0];  // [16384,1024]
  const float* W1 = (const float*)d_in[1];  // [4096,1024]
  const float* b1 = (const float*)d_in[2];  // [4096]
  const float* W2 = (const float*)d_in[3];  // [1024,4096]
  const float* b2 = (const float*)d_in[4];  // [1024]
  float* out = (float*)d_out;               // [16384,1024]

  const int M = 16384, H = 1024, F = 4096;

  unsigned short* xb  = (unsigned short*)d_ws;          // M*H bf16 (32 MiB)
  unsigned short* w1b = xb + (size_t)M * H;             // F*H bf16 (8 MiB)
  unsigned short* w2b = w1b + (size_t)F * H;            // H*F bf16 (8 MiB)
  unsigned short* act = w2b + (size_t)H * F;            // M*F bf16 (128 MiB)

  cvt_all<<<2048, 256, 0, stream>>>(x, W1, W2, xb, w1b, w2b,
                                    (M * H) / 4, (F * H) / 4);

  // GEMM1: act = relu(x @ W1^T + b1), bf16 out. M=16384, N=4096, K=1024.
  gemm8<1, 16><<<dim3((M / 256) * (F / 256)), 512, 0, stream>>>(xb, w1b, b1, act, H);
  // GEMM2: out = act @ W2^T + b2, f32 out. M=16384, N=1024, K=4096.
  gemm8<0, 4><<<dim3((M / 256) * (H / 256)), 512, 0, stream>>>(act, w2b, b2, out, F);
}